// Round 1
// baseline (41.427 us; speedup 1.0000x reference)
//
#include <hip/hip_runtime.h>
#include <math.h>

// Fenwick-tree deformation: out[t] = node[t] + out[t & (t-1)], t = 1..1024,
// per (k, channel) element. trans: [1025, 4096, 3] f32; rots: [1025, 4096, 4] f32.
// Output: trans [1024,4096,3] then normalized rots [1024,4096,4], f32, concat.

#define T_FRAMES 1024
#define CHUNK 32
#define NCHUNKS (T_FRAMES / CHUNK)  // 32

#define NT_COLS 3072  // K*3/4 float4 per row (translations)
#define NR_COLS 4096  // K*4/4 float4 per row (rotations)
#define TRANS_THREADS (NT_COLS * NCHUNKS)  // 98304
#define ROT_THREADS   (NR_COLS * NCHUNKS)  // 131072

__device__ __forceinline__ float4 f4add(float4 a, float4 b) {
    return make_float4(a.x + b.x, a.y + b.y, a.z + b.z, a.w + b.w);
}

__device__ __forceinline__ float4 f4norm(float4 o) {
    float n2 = o.x * o.x + o.y * o.y + o.z * o.z + o.w * o.w;
    float inv = 1.0f / fmaxf(sqrtf(n2), 1e-12f);
    return make_float4(o.x * inv, o.y * inv, o.z * inv, o.w * inv);
}

template <int NCOLS, bool NORM>
__device__ __forceinline__ void run_chunk(const float4* __restrict__ src,
                                          float4* __restrict__ dst, int id) {
    const int chunk = id / NCOLS;          // 0..31 (div by compile-time const)
    const int col = id - chunk * NCOLS;
    const int base = chunk * CHUNK;

    // carry = out[base] = sum over chain(chunk) of node[m*CHUNK]
    float4 carry = make_float4(0.f, 0.f, 0.f, 0.f);
    for (int b = chunk; b > 0; b &= (b - 1)) {
        carry = f4add(carry, src[(b * CHUNK) * NCOLS + col]);
    }

    // local Fenwick recurrence, fully unrolled so acc[] indices are static
    float4 acc[5];
#pragma unroll
    for (int r = 1; r < CHUNK; ++r) {
        float4 v = src[(base + r) * NCOLS + col];
        const int p = r & (r - 1);
        float4 s = v;
        if (p) s = f4add(s, acc[__builtin_ctz(p)]);
        acc[__builtin_ctz(r)] = s;
        float4 o = f4add(s, carry);
        if (NORM) o = f4norm(o);
        dst[(base + r - 1) * NCOLS + col] = o;
    }

    // boundary t = (chunk+1)*CHUNK: chain over multiples of CHUNK
    float4 s = make_float4(0.f, 0.f, 0.f, 0.f);
    for (int b = chunk + 1; b > 0; b &= (b - 1)) {
        s = f4add(s, src[(b * CHUNK) * NCOLS + col]);
    }
    if (NORM) s = f4norm(s);
    dst[(base + CHUNK - 1) * NCOLS + col] = s;
}

__global__ __launch_bounds__(256) void fenwick_deform_kernel(
    const float4* __restrict__ trans_in, const float4* __restrict__ rot_in,
    float4* __restrict__ trans_out, float4* __restrict__ rot_out) {
    const int gid = blockIdx.x * 256 + threadIdx.x;
    if (gid < TRANS_THREADS) {
        run_chunk<NT_COLS, false>(trans_in, trans_out, gid);
    } else {
        run_chunk<NR_COLS, true>(rot_in, rot_out, gid - TRANS_THREADS);
    }
}

extern "C" void kernel_launch(void* const* d_in, const int* in_sizes, int n_in,
                              void* d_out, int out_size, void* d_ws, size_t ws_size,
                              hipStream_t stream) {
    const float4* trans_in = (const float4*)d_in[0];  // [1025, 3072] float4
    const float4* rot_in = (const float4*)d_in[1];    // [1025, 4096] float4
    float* out = (float*)d_out;
    float4* trans_out = (float4*)out;                                   // [1024, 3072] f4
    float4* rot_out = (float4*)(out + (size_t)T_FRAMES * 4096 * 3);     // [1024, 4096] f4

    const int total = TRANS_THREADS + ROT_THREADS;  // 229376
    const int blocks = total / 256;                 // 896
    fenwick_deform_kernel<<<blocks, 256, 0, stream>>>(trans_in, rot_in, trans_out,
                                                      rot_out);
}

// Round 2
// 40.662 us; speedup vs baseline: 1.0188x; 1.0188x over previous
//
#include <hip/hip_runtime.h>
#include <math.h>

// Fenwick-tree deformation: out[t] = node[t] + out[t & (t-1)], t = 1..1024,
// per (k, channel) element. trans: [1025, 4096, 3] f32; rots: [1025, 4096, 4] f32.
// Output: trans [1024,4096,3] then normalized rots [1024,4096,4], f32, concat.
//
// R2: CHUNK 32->16 (2x threads, 1792 blocks) + all 15 chunk-rows loaded upfront
// into registers (static indices) for ~15 loads in flight per thread.

#define T_FRAMES 1024
#define CHUNK 16
#define NCHUNKS (T_FRAMES / CHUNK)  // 64

#define NT_COLS 3072  // K*3/4 float4 per row (translations)
#define NR_COLS 4096  // K*4/4 float4 per row (rotations)
#define TRANS_THREADS (NT_COLS * NCHUNKS)  // 196608
#define ROT_THREADS   (NR_COLS * NCHUNKS)  // 262144

__device__ __forceinline__ float4 f4add(float4 a, float4 b) {
    return make_float4(a.x + b.x, a.y + b.y, a.z + b.z, a.w + b.w);
}

__device__ __forceinline__ float4 f4norm(float4 o) {
    float n2 = o.x * o.x + o.y * o.y + o.z * o.z + o.w * o.w;
    float inv = 1.0f / fmaxf(sqrtf(n2), 1e-12f);
    return make_float4(o.x * inv, o.y * inv, o.z * inv, o.w * inv);
}

template <int NCOLS, bool NORM>
__device__ __forceinline__ void run_chunk(const float4* __restrict__ src,
                                          float4* __restrict__ dst, int id) {
    const int chunk = id / NCOLS;          // 0..63 (div by compile-time const)
    const int col = id - chunk * NCOLS;
    const int base = chunk * CHUNK;

    // Issue all 15 local-row loads upfront (static indices -> registers).
    float4 v[CHUNK];
#pragma unroll
    for (int r = 1; r < CHUNK; ++r) {
        v[r] = src[(size_t)(base + r) * NCOLS + col];
    }

    // carry = out[base] = sum over chain(chunk) of node[m*CHUNK]  (<=6 loads,
    // independent addresses, rows shared by all threads of the chunk -> L2-hot)
    float4 carry = make_float4(0.f, 0.f, 0.f, 0.f);
    for (int b = chunk; b > 0; b &= (b - 1)) {
        carry = f4add(carry, src[(size_t)(b * CHUNK) * NCOLS + col]);
    }

    // boundary t = (chunk+1)*CHUNK: chain over multiples of CHUNK
    float4 sb = make_float4(0.f, 0.f, 0.f, 0.f);
    for (int b = chunk + 1; b > 0; b &= (b - 1)) {
        sb = f4add(sb, src[(size_t)(b * CHUNK) * NCOLS + col]);
    }

    // In-place local Fenwick prefix: v[r] += v[r & (r-1)] (already finalized).
#pragma unroll
    for (int r = 2; r < CHUNK; ++r) {
        const int p = r & (r - 1);
        if (p) v[r] = f4add(v[r], v[p]);
    }

    // Stores: out[base + r - 1] = local_sum(r) + carry.
#pragma unroll
    for (int r = 1; r < CHUNK; ++r) {
        float4 o = f4add(v[r], carry);
        if (NORM) o = f4norm(o);
        dst[(size_t)(base + r - 1) * NCOLS + col] = o;
    }
    float4 o = NORM ? f4norm(sb) : sb;
    dst[(size_t)(base + CHUNK - 1) * NCOLS + col] = o;
}

__global__ __launch_bounds__(256) void fenwick_deform_kernel(
    const float4* __restrict__ trans_in, const float4* __restrict__ rot_in,
    float4* __restrict__ trans_out, float4* __restrict__ rot_out) {
    const int gid = blockIdx.x * 256 + threadIdx.x;
    if (gid < TRANS_THREADS) {
        run_chunk<NT_COLS, false>(trans_in, trans_out, gid);
    } else {
        run_chunk<NR_COLS, true>(rot_in, rot_out, gid - TRANS_THREADS);
    }
}

extern "C" void kernel_launch(void* const* d_in, const int* in_sizes, int n_in,
                              void* d_out, int out_size, void* d_ws, size_t ws_size,
                              hipStream_t stream) {
    const float4* trans_in = (const float4*)d_in[0];  // [1025, 3072] float4
    const float4* rot_in = (const float4*)d_in[1];    // [1025, 4096] float4
    float* out = (float*)d_out;
    float4* trans_out = (float4*)out;                                // [1024, 3072] f4
    float4* rot_out = (float4*)(out + (size_t)T_FRAMES * 4096 * 3);  // [1024, 4096] f4

    const int total = TRANS_THREADS + ROT_THREADS;  // 458752
    const int blocks = total / 256;                 // 1792
    fenwick_deform_kernel<<<blocks, 256, 0, stream>>>(trans_in, rot_in, trans_out,
                                                      rot_out);
}

// Round 4
// 40.554 us; speedup vs baseline: 1.0215x; 1.0027x over previous
//
#include <hip/hip_runtime.h>
#include <math.h>

// Fenwick-tree deformation: out[t] = node[t] + out[t & (t-1)], t = 1..1024,
// per (k, channel) element. trans: [1025, 4096, 3] f32; rots: [1025, 4096, 4] f32.
// Output: trans [1024,4096,3] then normalized rots [1024,4096,4], f32, concat.
//
// R4 = R3 with compile fix: __builtin_nontemporal_store needs a NATIVE vector
// type (ext_vector_type), not HIP_vector_type. Non-temporal output stores so
// the 117 MB of writes stop evicting the 117 MB input from the 256 MB L3.

#define T_FRAMES 1024
#define CHUNK 16
#define NCHUNKS (T_FRAMES / CHUNK)  // 64

#define NT_COLS 3072  // K*3/4 float4 per row (translations)
#define NR_COLS 4096  // K*4/4 float4 per row (rotations)
#define TRANS_THREADS (NT_COLS * NCHUNKS)  // 196608
#define ROT_THREADS   (NR_COLS * NCHUNKS)  // 262144

typedef float nfloat4 __attribute__((ext_vector_type(4)));

__device__ __forceinline__ float4 f4add(float4 a, float4 b) {
    return make_float4(a.x + b.x, a.y + b.y, a.z + b.z, a.w + b.w);
}

__device__ __forceinline__ float4 f4norm(float4 o) {
    float n2 = o.x * o.x + o.y * o.y + o.z * o.z + o.w * o.w;
    float inv = 1.0f / fmaxf(sqrtf(n2), 1e-12f);
    return make_float4(o.x * inv, o.y * inv, o.z * inv, o.w * inv);
}

__device__ __forceinline__ void nt_store(float4* p, float4 v) {
    nfloat4 nv;
    nv.x = v.x; nv.y = v.y; nv.z = v.z; nv.w = v.w;
    __builtin_nontemporal_store(nv, (nfloat4*)p);
}

template <int NCOLS, bool NORM>
__device__ __forceinline__ void run_chunk(const float4* __restrict__ src,
                                          float4* __restrict__ dst, int id) {
    const int chunk = id / NCOLS;          // 0..63 (div by compile-time const)
    const int col = id - chunk * NCOLS;
    const int base = chunk * CHUNK;

    // Issue all 15 local-row loads upfront (static indices -> registers).
    float4 v[CHUNK];
#pragma unroll
    for (int r = 1; r < CHUNK; ++r) {
        v[r] = src[(size_t)(base + r) * NCOLS + col];
    }

    // carry = out[base] = sum over chain(chunk) of node[m*CHUNK]  (<=6 loads,
    // rows shared by all threads of the chunk -> L2-hot)
    float4 carry = make_float4(0.f, 0.f, 0.f, 0.f);
    for (int b = chunk; b > 0; b &= (b - 1)) {
        carry = f4add(carry, src[(size_t)(b * CHUNK) * NCOLS + col]);
    }

    // boundary t = (chunk+1)*CHUNK: chain over multiples of CHUNK
    float4 sb = make_float4(0.f, 0.f, 0.f, 0.f);
    for (int b = chunk + 1; b > 0; b &= (b - 1)) {
        sb = f4add(sb, src[(size_t)(b * CHUNK) * NCOLS + col]);
    }

    // In-place local Fenwick prefix: v[r] += v[r & (r-1)] (already finalized).
#pragma unroll
    for (int r = 2; r < CHUNK; ++r) {
        const int p = r & (r - 1);
        if (p) v[r] = f4add(v[r], v[p]);
    }

    // Stores: out[base + r - 1] = local_sum(r) + carry.  Non-temporal.
#pragma unroll
    for (int r = 1; r < CHUNK; ++r) {
        float4 o = f4add(v[r], carry);
        if (NORM) o = f4norm(o);
        nt_store(&dst[(size_t)(base + r - 1) * NCOLS + col], o);
    }
    float4 o = NORM ? f4norm(sb) : sb;
    nt_store(&dst[(size_t)(base + CHUNK - 1) * NCOLS + col], o);
}

__global__ __launch_bounds__(256) void fenwick_deform_kernel(
    const float4* __restrict__ trans_in, const float4* __restrict__ rot_in,
    float4* __restrict__ trans_out, float4* __restrict__ rot_out) {
    const int gid = blockIdx.x * 256 + threadIdx.x;
    if (gid < TRANS_THREADS) {
        run_chunk<NT_COLS, false>(trans_in, trans_out, gid);
    } else {
        run_chunk<NR_COLS, true>(rot_in, rot_out, gid - TRANS_THREADS);
    }
}

extern "C" void kernel_launch(void* const* d_in, const int* in_sizes, int n_in,
                              void* d_out, int out_size, void* d_ws, size_t ws_size,
                              hipStream_t stream) {
    const float4* trans_in = (const float4*)d_in[0];  // [1025, 3072] float4
    const float4* rot_in = (const float4*)d_in[1];    // [1025, 4096] float4
    float* out = (float*)d_out;
    float4* trans_out = (float4*)out;                                // [1024, 3072] f4
    float4* rot_out = (float4*)(out + (size_t)T_FRAMES * 4096 * 3);  // [1024, 4096] f4

    const int total = TRANS_THREADS + ROT_THREADS;  // 458752
    const int blocks = total / 256;                 // 1792
    fenwick_deform_kernel<<<blocks, 256, 0, stream>>>(trans_in, rot_in, trans_out,
                                                      rot_out);
}